// Round 1
// 764.934 us; speedup vs baseline: 1.0443x; 1.0443x over previous
//
#include <hip/hip_runtime.h>
#include <hip/hip_bf16.h>

#define N_NODES 20000
#define N_EDGES 100000
#define HID 512
#define G3 1536   // 3*HID
#define NH 8
#define OD 64

typedef __hip_bfloat16 bf16;
typedef __attribute__((ext_vector_type(8))) short bf16x8;   // 8 bf16 = 4 VGPRs
typedef __attribute__((ext_vector_type(4))) float f32x4;

__device__ __forceinline__ float frcp(float x) { return __builtin_amdgcn_rcpf(x); }
__device__ __forceinline__ float fsig(float x) { return frcp(1.0f + __expf(-x)); }
// saturation-safe fast tanh (rcp-based)
__device__ __forceinline__ float ftanh(float x) { return 1.0f - 2.0f * frcp(__expf(2.0f * x) + 1.0f); }
__device__ __forceinline__ float b2f(bf16 b) { return __bfloat162float(b); }
__device__ __forceinline__ bf16 f2b(float f) { return __float2bfloat16(f); }
__device__ __forceinline__ float bs2f(short s) {
    return __uint_as_float(((unsigned)(unsigned short)s) << 16);
}
__device__ __forceinline__ float us2f(unsigned short s) {
    return __uint_as_float(((unsigned)s) << 16);
}
__device__ __forceinline__ short f2bs(float f) {
    bf16 b = __float2bfloat16(f);
    return *reinterpret_cast<short*>(&b);
}
__device__ __forceinline__ unsigned ford(float f) {
    unsigned u = __float_as_uint(f);
    return (u & 0x80000000u) ? ~u : (u | 0x80000000u);
}
__device__ __forceinline__ float iford(unsigned u) {
    return __uint_as_float((u & 0x80000000u) ? (u & 0x7fffffffu) : ~u);
}

// async global->LDS 16B; falls back to manual copy if builtin missing
__device__ __forceinline__ void g2l16(const void* g, void* l) {
#if __has_builtin(__builtin_amdgcn_global_load_lds)
    __builtin_amdgcn_global_load_lds((const __attribute__((address_space(1))) char*)g,
                                     (__attribute__((address_space(3))) char*)l, 16, 0, 0);
#else
    *(bf16x8*)l = *(const bf16x8*)g;
#endif
}

// G / GH2 layout: gate-interleaved  X[n*1536 + k*3 + g]; H1/h2: row-major [n][512]

// ---- K0: prep weights.
__global__ __launch_bounds__(256) void k_prep(const float* __restrict__ Whh,
                                              const float* __restrict__ Wih,
                                              bf16* __restrict__ WTs,
                                              float* __restrict__ WIT) {
    int t = blockIdx.x * 256 + threadIdx.x;   // 768 blocks -> 196608 exactly
    if (t < 98304) {
        int T = t >> 10, c = (t >> 6) & 15, l = t & 63;
        int n = T * 16 + (l & 15);
        int k = c * 32 + ((l >> 4) << 3);
        const float* src = Whh + (size_t)n * 512 + k;
        bf16x8 v;
#pragma unroll
        for (int j = 0; j < 8; ++j) v[j] = f2bs(src[j]);
        *(bf16x8*)(WTs + (size_t)t * 8) = v;
    } else {
        int u = t - 98304;          // WIT[d][j] = Wih[j][d]
        int d = u / 1536, j = u % 1536;
        WIT[u] = Wih[(size_t)j * 64 + d];
    }
}

// ---- CSR build: count / scan / fill
__global__ __launch_bounds__(256) void k_count(const int* __restrict__ dst,
                                               unsigned* __restrict__ cnt) {
    int e = blockIdx.x * 256 + threadIdx.x;
    if (e < N_EDGES) atomicAdd(&cnt[dst[e]], 1u);
}

#define SCAN_CH 79
__global__ __launch_bounds__(256) void k_scan(const unsigned* __restrict__ cnt,
                                              unsigned* __restrict__ base,
                                              unsigned* __restrict__ cursor) {
    __shared__ unsigned ls[256];
    int t = threadIdx.x;
    int s0 = t * SCAN_CH;
    int s1 = s0 + SCAN_CH < N_NODES ? s0 + SCAN_CH : N_NODES;
    unsigned s = 0;
    for (int i = s0; i < s1; ++i) s += cnt[i];
    ls[t] = s;
    __syncthreads();
    for (int d = 1; d < 256; d <<= 1) {
        unsigned v = (t >= d) ? ls[t - d] : 0u;
        __syncthreads();
        ls[t] += v;
        __syncthreads();
    }
    unsigned run = ls[t] - s;
    for (int i = s0; i < s1; ++i) {
        base[i] = run; cursor[i] = run; run += cnt[i];
    }
    if (t == 255) base[N_NODES] = ls[255];
}

__global__ __launch_bounds__(256) void k_fill(const int* __restrict__ dst,
                                              unsigned* __restrict__ cursor,
                                              unsigned* __restrict__ csr) {
    int e = blockIdx.x * 256 + threadIdx.x;
    if (e < N_EDGES) {
        unsigned p = atomicAdd(&cursor[dst[e]], 1u);
        csr[p] = (unsigned)e;
    }
}

// ---- K1: G[n][k][g] = features[n].W_ih + b_ih (interleaved); also H1[n][k] (free)
__global__ __launch_bounds__(256) void k_gi(const float* __restrict__ feat,
                                            const float* __restrict__ WIT,
                                            const float* __restrict__ b_ih,
                                            const float* __restrict__ b_hh,
                                            bf16* __restrict__ G,
                                            bf16* __restrict__ H1) {
    __shared__ float fs[16][64];
    const int n0 = blockIdx.x * 16;
    const int k = blockIdx.y * 256 + threadIdx.x;
    for (int i = threadIdx.x; i < 16 * 64; i += 256)
        fs[0][i] = feat[(size_t)n0 * 64 + i];
    __syncthreads();
    float acc[3][16];
#pragma unroll
    for (int g = 0; g < 3; ++g) {
        float b = b_ih[g * 512 + k];
#pragma unroll
        for (int e = 0; e < 16; ++e) acc[g][e] = b;
    }
    for (int d = 0; d < 64; d += 4) {
        float w[3][4];
#pragma unroll
        for (int u = 0; u < 4; ++u)
#pragma unroll
            for (int g = 0; g < 3; ++g)
                w[g][u] = WIT[(size_t)(d + u) * G3 + g * 512 + k];
#pragma unroll
        for (int e = 0; e < 16; ++e) {
            float4 f = *(const float4*)&fs[e][d];
#pragma unroll
            for (int g = 0; g < 3; ++g)
                acc[g][e] += w[g][0] * f.x + w[g][1] * f.y + w[g][2] * f.z + w[g][3] * f.w;
        }
    }
    const float br = b_hh[k], bz = b_hh[512 + k], bn = b_hh[1024 + k];
#pragma unroll
    for (int e = 0; e < 16; ++e) {
        bf16* dst = G + (size_t)(n0 + e) * G3 + k * 3;
        dst[0] = f2b(acc[0][e]);
        dst[1] = f2b(acc[1][e]);
        dst[2] = f2b(acc[2][e]);
        float r1 = fsig(acc[0][e] + br);
        float z1 = fsig(acc[1][e] + bz);
        float n1 = ftanh(acc[2][e] + r1 * bn);
        H1[(size_t)(n0 + e) * HID + k] = f2b((1.0f - z1) * n1);
    }
}

// ---- K2: GH2[n] = H1[n] @ W_hh^T + b_hh. M=64/block, per-gate double-buffered
// staging (2x16KB LDS): stage next phase -> compute current -> one barrier.
__global__ __launch_bounds__(256, 4) void k_gh2(const bf16* __restrict__ H1,
                                                const bf16* __restrict__ WTs,
                                                const float* __restrict__ b_hh,
                                                bf16* __restrict__ GH2) {
    __shared__ short Bs[2][8192];   // 32 KB
    const int tid = threadIdx.x;
    const int wave = tid >> 6, lane = tid & 63;
    const int m0 = blockIdx.x * 64;
    const int k0 = (lane >> 4) << 3;

    bf16x8 afrag[16];
    {
        int row = m0 + wave * 16 + (lane & 15);
        int ar = row < N_NODES ? row : N_NODES - 1;
#pragma unroll
        for (int c = 0; c < 16; ++c)
            afrag[c] = *(const bf16x8*)(H1 + (size_t)ar * HID + c * 32 + k0);
    }

    const int col = lane & 15;
    const int qb = (lane >> 4) << 2;
    const int boff = lane * 8;

    // prologue: stage (jt=0, gate=0) into buf 0
#pragma unroll
    for (int i = 0; i < 4; ++i) {
        int q = tid + i * 256;
        g2l16(WTs + (size_t)q * 8, &Bs[0][q * 8]);
    }
    __syncthreads();

    int cur = 0;
    for (int jt = 0; jt < 32; ++jt) {
        const int cj = jt * 16 + col;
        f32x4 a0 = {0, 0, 0, 0}, a1 = {0, 0, 0, 0}, a2 = {0, 0, 0, 0};
        const float br = b_hh[cj], bz = b_hh[512 + cj], bn = b_hh[1024 + cj];
        // ---- phase gate 0: stage gate1, compute gate0
        {
#pragma unroll
            for (int i = 0; i < 4; ++i) {
                int q = tid + i * 256;
                g2l16(WTs + 262144 + (size_t)jt * 8192 + q * 8, &Bs[cur ^ 1][q * 8]);
            }
            const short* cb = &Bs[cur][0];
#pragma unroll
            for (int c = 0; c < 16; ++c) {
                bf16x8 b = *(const bf16x8*)&cb[c * 512 + boff];
                a0 = __builtin_amdgcn_mfma_f32_16x16x32_bf16(afrag[c], b, a0, 0, 0, 0);
            }
            __syncthreads();
            cur ^= 1;
        }
        // ---- phase gate 1: stage gate2, compute gate1
        {
#pragma unroll
            for (int i = 0; i < 4; ++i) {
                int q = tid + i * 256;
                g2l16(WTs + 524288 + (size_t)jt * 8192 + q * 8, &Bs[cur ^ 1][q * 8]);
            }
            const short* cb = &Bs[cur][0];
#pragma unroll
            for (int c = 0; c < 16; ++c) {
                bf16x8 b = *(const bf16x8*)&cb[c * 512 + boff];
                a1 = __builtin_amdgcn_mfma_f32_16x16x32_bf16(afrag[c], b, a1, 0, 0, 0);
            }
            __syncthreads();
            cur ^= 1;
        }
        // ---- phase gate 2: stage next jt gate0, compute gate2, epilogue
        {
            if (jt < 31) {
#pragma unroll
                for (int i = 0; i < 4; ++i) {
                    int q = tid + i * 256;
                    g2l16(WTs + (size_t)(jt + 1) * 8192 + q * 8, &Bs[cur ^ 1][q * 8]);
                }
            }
            const short* cb = &Bs[cur][0];
#pragma unroll
            for (int c = 0; c < 16; ++c) {
                bf16x8 b = *(const bf16x8*)&cb[c * 512 + boff];
                a2 = __builtin_amdgcn_mfma_f32_16x16x32_bf16(afrag[c], b, a2, 0, 0, 0);
            }
#pragma unroll
            for (int q = 0; q < 4; ++q) {
                int e = m0 + wave * 16 + qb + q;
                if (e < N_NODES) {
                    bf16* dst = GH2 + (size_t)e * G3 + cj * 3;
                    dst[0] = f2b(a0[q] + br);
                    dst[1] = f2b(a1[q] + bz);
                    dst[2] = f2b(a2[q] + bn);
                }
            }
            __syncthreads();
            cur ^= 1;
        }
    }
}

// ---- K3: per-edge h2 = GRUstep2(G[i1], GH2[i0], H1[i0]) elementwise
__global__ __launch_bounds__(256) void k_h2(const bf16* __restrict__ G,
                                            const bf16* __restrict__ GH2,
                                            const bf16* __restrict__ H1,
                                            const int* __restrict__ emi,
                                            bf16* __restrict__ h2) {
    size_t i = (size_t)blockIdx.x * 256 + threadIdx.x;   // 25000 blocks exactly
    int e = (int)(i >> 6);
    int kc = (int)(i & 63) * 8;
    int i0 = emi[(size_t)e * 3 + 0];
    int i1 = emi[(size_t)e * 3 + 1];
    const bf16* g1p = G + (size_t)i1 * G3 + kc * 3;
    const bf16* ghp = GH2 + (size_t)i0 * G3 + kc * 3;
    bf16x8 h1v = *(const bf16x8*)(H1 + (size_t)i0 * HID + kc);
    short s1[24], sh[24];
    {
        bf16x8 a0 = *(const bf16x8*)g1p, a1 = *(const bf16x8*)(g1p + 8), a2 = *(const bf16x8*)(g1p + 16);
        bf16x8 c0 = *(const bf16x8*)ghp, c1 = *(const bf16x8*)(ghp + 8), c2 = *(const bf16x8*)(ghp + 16);
#pragma unroll
        for (int j = 0; j < 8; ++j) {
            s1[j] = a0[j]; s1[8 + j] = a1[j]; s1[16 + j] = a2[j];
            sh[j] = c0[j]; sh[8 + j] = c1[j]; sh[16 + j] = c2[j];
        }
    }
    bf16x8 out;
#pragma unroll
    for (int j = 0; j < 8; ++j) {
        float r = fsig(bs2f(s1[j * 3 + 0]) + bs2f(sh[j * 3 + 0]));
        float z = fsig(bs2f(s1[j * 3 + 1]) + bs2f(sh[j * 3 + 1]));
        float n = ftanh(bs2f(s1[j * 3 + 2]) + r * bs2f(sh[j * 3 + 2]));
        out[j] = f2bs((1.0f - z) * n + z * bs2f(h1v[j]));
    }
    *(bf16x8*)(h2 + (size_t)e * HID + kc) = out;
}

// ---- K4: gh3 = h2 @ W_hh^T; h3 = GRUstep3(G[i2], gh3+b_hh, h2) in-place.
// Per-gate double-buffered staging (2x16KB LDS, 4 blocks/CU): the next phase's
// global_load_lds is issued BEFORE the current phase's MFMAs, so the vmcnt(0)
// drain at __syncthreads lands after the latency is covered (T3 2-phase lite).
__global__ __launch_bounds__(256, 4) void k_gemm3(const bf16* __restrict__ G,
                                                  const bf16* __restrict__ WTs,
                                                  const float* __restrict__ b_hh,
                                                  const int* __restrict__ emi,
                                                  bf16* __restrict__ h2) {
    __shared__ short Bs[2][8192];   // 32 KB
    __shared__ int si2[64];
    const int tid = threadIdx.x;
    const int wave = tid >> 6, lane = tid & 63;
    const int m0 = blockIdx.x * 64;
    if (tid < 64) {
        int e = m0 + tid;
        si2[tid] = emi[(size_t)(e < N_EDGES ? e : N_EDGES - 1) * 3 + 2];
    }
    const int k0 = (lane >> 4) << 3;

    // A frags: one 16-row m-tile per wave, full K in regs
    bf16x8 afrag[16];
    {
        int row = m0 + wave * 16 + (lane & 15);
        int ar = row < N_EDGES ? row : N_EDGES - 1;
#pragma unroll
        for (int c = 0; c < 16; ++c)
            afrag[c] = *(const bf16x8*)(h2 + (size_t)ar * HID + c * 32 + k0);
    }

    const int col = lane & 15;
    const int qb = (lane >> 4) << 2;
    const int boff = lane * 8;

    // prologue: stage (jt=0, gate=0) into buf 0 (also covers si2 visibility)
#pragma unroll
    for (int i = 0; i < 4; ++i) {
        int q = tid + i * 256;
        g2l16(WTs + (size_t)q * 8, &Bs[0][q * 8]);
    }
    __syncthreads();

    int cur = 0;
    for (int jt = 0; jt < 32; ++jt) {
        const int cj = jt * 16 + col;
        f32x4 a0 = {0, 0, 0, 0}, a1 = {0, 0, 0, 0}, a2 = {0, 0, 0, 0};
        float br, bz, bn;
        unsigned short pg[4][3], ph[4];
        // ---- phase gate 0: prefetch epilogue operands + stage gate1, compute gate0
        {
            // gathered epilogue prefetch first (longest latency)
            br = b_hh[cj]; bz = b_hh[512 + cj]; bn = b_hh[1024 + cj];
#pragma unroll
            for (int q = 0; q < 4; ++q) {
                int li = wave * 16 + qb + q;
                int e = m0 + li;
                int ec = e < N_EDGES ? e : N_EDGES - 1;
                const unsigned short* g2p =
                    (const unsigned short*)(G + (size_t)si2[li] * G3 + cj * 3);
                pg[q][0] = g2p[0]; pg[q][1] = g2p[1]; pg[q][2] = g2p[2];
                ph[q] = ((const unsigned short*)h2)[(size_t)ec * HID + cj];
            }
#pragma unroll
            for (int i = 0; i < 4; ++i) {
                int q = tid + i * 256;
                g2l16(WTs + 262144 + (size_t)jt * 8192 + q * 8, &Bs[cur ^ 1][q * 8]);
            }
            const short* cb = &Bs[cur][0];
#pragma unroll
            for (int c = 0; c < 16; ++c) {
                bf16x8 b = *(const bf16x8*)&cb[c * 512 + boff];
                a0 = __builtin_amdgcn_mfma_f32_16x16x32_bf16(afrag[c], b, a0, 0, 0, 0);
            }
            __syncthreads();
            cur ^= 1;
        }
        // ---- phase gate 1: stage gate2, compute gate1
        {
#pragma unroll
            for (int i = 0; i < 4; ++i) {
                int q = tid + i * 256;
                g2l16(WTs + 524288 + (size_t)jt * 8192 + q * 8, &Bs[cur ^ 1][q * 8]);
            }
            const short* cb = &Bs[cur][0];
#pragma unroll
            for (int c = 0; c < 16; ++c) {
                bf16x8 b = *(const bf16x8*)&cb[c * 512 + boff];
                a1 = __builtin_amdgcn_mfma_f32_16x16x32_bf16(afrag[c], b, a1, 0, 0, 0);
            }
            __syncthreads();
            cur ^= 1;
        }
        // ---- phase gate 2: stage next jt gate0, compute gate2, fused GRU epilogue
        {
            if (jt < 31) {
#pragma unroll
                for (int i = 0; i < 4; ++i) {
                    int q = tid + i * 256;
                    g2l16(WTs + (size_t)(jt + 1) * 8192 + q * 8, &Bs[cur ^ 1][q * 8]);
                }
            }
            const short* cb = &Bs[cur][0];
#pragma unroll
            for (int c = 0; c < 16; ++c) {
                bf16x8 b = *(const bf16x8*)&cb[c * 512 + boff];
                a2 = __builtin_amdgcn_mfma_f32_16x16x32_bf16(afrag[c], b, a2, 0, 0, 0);
            }
            // epilogue: pure compute + store (operands prefetched at gate0)
#pragma unroll
            for (int q = 0; q < 4; ++q) {
                int e = m0 + wave * 16 + qb + q;
                if (e < N_EDGES) {
                    float r = fsig(us2f(pg[q][0]) + a0[q] + br);
                    float z = fsig(us2f(pg[q][1]) + a1[q] + bz);
                    float ng = ftanh(us2f(pg[q][2]) + r * (a2[q] + bn));
                    h2[(size_t)e * HID + cj] = f2b((1.0f - z) * ng + z * us2f(ph[q]));
                }
            }
            __syncthreads();
            cur ^= 1;
        }
    }
}

// ---- K6: attention logits + leaky relu + segment max
__global__ __launch_bounds__(256) void k_logits(const bf16* __restrict__ eft,
                                                const float* __restrict__ attn,
                                                const int* __restrict__ dst,
                                                float* __restrict__ a,
                                                unsigned* __restrict__ amax) {
    int i = blockIdx.x * 256 + threadIdx.x;  // E*NH exactly
    int e = i >> 3, h = i & 7;
    const __hip_bfloat162* f2 = (const __hip_bfloat162*)(eft + (size_t)e * HID + h * OD);
    const float* at = attn + h * OD;
    float s = 0.f;
#pragma unroll
    for (int d = 0; d < OD / 2; ++d) {
        float2 fv = __bfloat1622float2(f2[d]);
        s += fv.x * at[2 * d] + fv.y * at[2 * d + 1];
    }
    s = (s >= 0.f) ? s : 0.01f * s;
    a[i] = s;
    atomicMax(&amax[(size_t)dst[e] * NH + h], ford(s));
}

// ---- K7: ea = exp(a - amax[dst]); denom += ea
__global__ __launch_bounds__(256) void k_ea(const int* __restrict__ dst,
                                            const unsigned* __restrict__ amax,
                                            float* __restrict__ a,
                                            float* __restrict__ denom) {
    int i = blockIdx.x * 256 + threadIdx.x;
    int e = i >> 3, h = i & 7;
    float m = iford(amax[(size_t)dst[e] * NH + h]);
    float v = __expf(a[i] - m);
    a[i] = v;
    atomicAdd(&denom[(size_t)dst[e] * NH + h], v);
}

// ---- K8: out[n][k] = sum_e eft[e][k]*ea[e][h] / denom[n][h]   (CSR, no atomics)
__global__ __launch_bounds__(256) void k_out(const bf16* __restrict__ eft,
                                             const float* __restrict__ a,
                                             const float* __restrict__ denom,
                                             const unsigned* __restrict__ base,
                                             const unsigned* __restrict__ csr,
                                             float* __restrict__ out) {
    int n = blockIdx.x;
    int k = blockIdx.y * 256 + threadIdx.x;
    int h = k >> 6;
    unsigned b0 = base[n], b1 = base[n + 1];
    float rden = (b1 > b0) ? frcp(denom[(size_t)n * NH + h]) : 0.0f;
    float acc = 0.f;
    for (unsigned i = b0; i < b1; ++i) {
        unsigned e = csr[i];
        float al = a[(size_t)e * NH + h];
        acc += b2f(eft[(size_t)e * HID + k]) * al;
    }
    out[(size_t)n * HID + k] = acc * rden;
}

extern "C" void kernel_launch(void* const* d_in, const int* in_sizes, int n_in,
                              void* d_out, int out_size, void* d_ws, size_t ws_size,
                              hipStream_t stream) {
    (void)in_sizes; (void)n_in; (void)ws_size; (void)out_size;
    const float* feat = (const float*)d_in[0];
    const float* W_ih = (const float*)d_in[1];
    const float* W_hh = (const float*)d_in[2];
    const float* b_ih = (const float*)d_in[3];
    const float* b_hh = (const float*)d_in[4];
    const float* attn = (const float*)d_in[5];
    const int* emi = (const int*)d_in[6];
    const int* dst = (const int*)d_in[7];
    float* out = (float*)d_out;

    // workspace layout (bytes) — total ~252.8 MB (proven-safe)
    char* ws = (char*)d_ws;
    bf16* G = (bf16*)ws;                               // 61,440,000 B (interleaved)
    bf16* GH2 = (bf16*)(ws + 61440000);                // 61,440,000 B (interleaved)
    bf16* h2 = (bf16*)(ws + 122880000);                // 102,400,000 B (row-major; h3 in-place)
    bf16* WTs = (bf16*)(ws + 225280000);               // 1,572,864 B
    float* WIT = (float*)(ws + 226852864);             // 393,216 B
    float* a = (float*)(ws + 227246080);               // 3,200,000 B
    unsigned* amax = (unsigned*)(ws + 230446080);      // 640,000 B
    float* denom = (float*)(ws + 231086080);           // 640,000 B
    unsigned* cnt = (unsigned*)(ws + 231726080);       // 80,000 B
    unsigned* base = (unsigned*)(ws + 231806080);      // 80,008 B (20001 u32, pad)
    unsigned* cursor = (unsigned*)(ws + 231886088);    // 80,000 B
    unsigned* csr = (unsigned*)(ws + 231966088);       // 400,000 B
    bf16* H1 = (bf16*)(ws + 232366088);                // 20,480,000 B -> end 252,846,088

    // zero amax + denom + cnt (contiguous)
    (void)hipMemsetAsync(amax, 0, 1360000, stream);

    k_prep<<<768, 256, 0, stream>>>(W_hh, W_ih, WTs, WIT);
    k_count<<<391, 256, 0, stream>>>(dst, cnt);
    k_scan<<<1, 256, 0, stream>>>(cnt, base, cursor);
    k_fill<<<391, 256, 0, stream>>>(dst, cursor, csr);
    k_gi<<<dim3(1250, 2), 256, 0, stream>>>(feat, WIT, b_ih, b_hh, G, H1);
    k_gh2<<<313, 256, 0, stream>>>(H1, WTs, b_hh, GH2);
    k_h2<<<25000, 256, 0, stream>>>(G, GH2, H1, emi, h2);
    k_gemm3<<<1563, 256, 0, stream>>>(G, WTs, b_hh, emi, h2);
    k_logits<<<3125, 256, 0, stream>>>(h2, attn, dst, a, amax);
    k_ea<<<3125, 256, 0, stream>>>(dst, amax, a, denom);
    k_out<<<dim3(N_NODES, 2), 256, 0, stream>>>(h2, a, denom, base, csr, out);
}